// Round 8
// baseline (387.265 us; speedup 1.0000x reference)
//
#include <hip/hip_runtime.h>
#include <cstdint>
#include <cstddef>

#define B_    16
#define C_    256
#define HW_   64
#define N_    4096      // 64*64 spatial
#define K_    512
#define NROW_ 65536     // B_*N_
#define QCAP  8192
#define MARGIN 0.03f

typedef __attribute__((ext_vector_type(8))) __bf16 bf16x8;
typedef __attribute__((ext_vector_type(4))) float floatx4;
typedef __attribute__((address_space(3))) __bf16 lds_bf16;
typedef __attribute__((address_space(1))) const __bf16 glob_bf16;

struct P2 { float v1; int k1; float v2; int k2; };

__device__ __forceinline__ bool lexless(float v, int k, float bv, int bk) {
    return (v < bv) || (v == bv && k < bk);
}
__device__ __forceinline__ void ins2(float v, int k, float& v1, int& k1, float& v2, int& k2) {
    if (lexless(v, k, v1, k1)) { v2 = v1; k2 = k1; v1 = v; k1 = k; }
    else if (lexless(v, k, v2, k2)) { v2 = v; k2 = k; }
}

// Apack (in d_out!): [Mtile 1024][ct 8][plane 2][q 4][m 64][i 8] bf16 = 64 MiB.
// Bpack:             [ct 8][plane 2][q 4][n 512][i 8] bf16 = 512 KB.
// Both are byte-identical to their LDS tiles -> pure linear global_load_lds.

// ---------------- kernel 1: codebook prep: e2 + packed B tiles + zeroing ------
__global__ void prep_kernel(const float* __restrict__ cb, float* __restrict__ e2,
                            __bf16* __restrict__ Bpack, double* __restrict__ lossAcc,
                            int* __restrict__ qcount) {
    int n = blockIdx.x, t = threadIdx.x;
    if (n == 0 && t == 0) { *lossAcc = 0.0; *qcount = 0; }
    float4 v = *(const float4*)(cb + (size_t)n * C_ + t * 4);
    float vv[4] = {v.x, v.y, v.z, v.w};
    __bf16 h[4], l[4];
    float s = 0.f;
    #pragma unroll
    for (int i = 0; i < 4; ++i) {
        h[i] = (__bf16)vv[i];
        l[i] = (__bf16)(vv[i] - (float)h[i]);
        s = fmaf(vv[i], vv[i], s);
    }
    // c = t*4+j: ct=t>>3, q=(t>>1)&3, i0=(t&1)*4
    int ct = t >> 3, q = (t >> 1) & 3, i0 = (t & 1) * 4;
    size_t base = (size_t)ct * 32768;
    *(ushort4*)&Bpack[base + ((size_t)(0 * 4 + q) * 512 + n) * 8 + i0] = *(ushort4*)h;
    *(ushort4*)&Bpack[base + ((size_t)(1 * 4 + q) * 512 + n) * 8 + i0] = *(ushort4*)l;
    #pragma unroll
    for (int off = 32; off; off >>= 1) s += __shfl_down(s, off);
    if (t == 0) e2[n] = s;
}

// ---------------- kernel 2: pq -> packed A tiles (hi/lo split) + x2 -----------
// One block per Mtile (64 rows). Reads pq coalesced (no barriers between loads),
// transposes via LDS, writes dense DMA-ready tiles.
__global__ void pack_kernel(const float* __restrict__ pq, __bf16* __restrict__ Apack,
                            float* __restrict__ x2) {
    const int Mtile = blockIdx.x, tid = threadIdx.x;
    const int b = Mtile >> 6;
    const int s0 = (Mtile * 64) & 4095;
    __shared__ float T[64][65];     // [c_local][s_local], pad 65
    __shared__ float xs[4][64];

    const int cl = tid >> 2, sq = (tid & 3) * 16;   // stage map
    const int q = tid >> 6, m = tid & 63;           // split map
    float x2part = 0.f;

    for (int cc = 0; cc < 4; ++cc) {
        __syncthreads();
        const float* src = pq + (size_t)b * (C_ * N_) + (size_t)(cc * 64 + cl) * N_ + s0 + sq;
        float4 v0 = ((const float4*)src)[0];
        float4 v1 = ((const float4*)src)[1];
        float4 v2 = ((const float4*)src)[2];
        float4 v3 = ((const float4*)src)[3];
        *(float4*)&T[cl][sq + 0]  = v0;
        *(float4*)&T[cl][sq + 4]  = v1;
        *(float4*)&T[cl][sq + 8]  = v2;
        *(float4*)&T[cl][sq + 12] = v3;
        __syncthreads();
        #pragma unroll
        for (int cs = 0; cs < 2; ++cs) {
            const int ct = cc * 2 + cs;
            bf16x8 hi, lo;
            #pragma unroll
            for (int i = 0; i < 8; ++i) {
                float x = T[cs * 32 + q * 8 + i][m];
                __bf16 h = (__bf16)x;
                hi[i] = h;
                lo[i] = (__bf16)(x - (float)h);
                x2part = fmaf(x, x, x2part);
            }
            __bf16* dst = Apack + ((size_t)Mtile * 8 + ct) * 4096;
            *(bf16x8*)&dst[((size_t)(0 * 4 + q) * 64 + m) * 8] = hi;   // hi plane
            *(bf16x8*)&dst[((size_t)(1 * 4 + q) * 64 + m) * 8] = lo;   // lo plane
        }
    }
    xs[q][m] = x2part;
    __syncthreads();
    if (tid < 64)
        x2[Mtile * 64 + tid] = xs[0][tid] + xs[1][tid] + xs[2][tid] + xs[3][tid];
}

// ---------------- kernel 3: pure-DMA split-bf16 MFMA GEMM + top-2 over 512 ----
// grid 512 (2 resident/CU, one pass); each block does 2 Mtiles sequentially.
// K-loop has ZERO VALU and ZERO pq access: 18 DMA instrs + 24 ds_read + 96 MFMA.
__launch_bounds__(256, 2)
__global__ void main_kernel(const __bf16* __restrict__ Apack,
                            const __bf16* __restrict__ Bpack,
                            const float* __restrict__ e2,
                            const float* __restrict__ x2,
                            int* __restrict__ idx, float* __restrict__ d2,
                            int2* __restrict__ queue, int* __restrict__ qcount) {
    const int tid = threadIdx.x;
    const int wave = tid >> 6, lane = tid & 63;
    const int lm = lane & 15, quad = lane >> 4;

    __shared__ __bf16 As[4096];        // [plane2][q4][m64][i8]  8 KB
    __shared__ __bf16 Bs[32768];       // [plane2][q4][n512][i8] 64 KB
    __shared__ P2 mergebuf[256];       // 4 KB

    for (int rep = 0; rep < 2; ++rep) {
        const int Mtile = blockIdx.x + rep * 512;

        floatx4 acc[4][8];
        #pragma unroll
        for (int i = 0; i < 4; ++i)
            #pragma unroll
            for (int j = 0; j < 8; ++j) acc[i][j] = (floatx4)0.f;

        for (int ct = 0; ct < 8; ++ct) {
            __syncthreads();                       // prev MFMA LDS reads done
            // ---- A: 2 DMA instrs/wave (2 KB) ----
            const __bf16* atile = Apack + ((size_t)Mtile * 8 + ct) * 4096;
            #pragma unroll
            for (int j = 0; j < 2; ++j) {
                int off = wave * 1024 + j * 512;
                __builtin_amdgcn_global_load_lds(
                    (const glob_bf16*)(atile + off + lane * 8),
                    (lds_bf16*)&As[off], 16, 0, 0);
            }
            // ---- B: 16 DMA instrs/wave (16 KB) ----
            const __bf16* btile = Bpack + ct * 32768;
            #pragma unroll
            for (int j = 0; j < 16; ++j) {
                int Lw = wave * 16 + j;
                __builtin_amdgcn_global_load_lds(
                    (const glob_bf16*)(btile + (size_t)(Lw * 64 + lane) * 8),
                    (lds_bf16*)&Bs[Lw * 512], 16, 0, 0);
            }
            __syncthreads();                       // vmcnt(0): tiles live

            // ---- MFMA: a1*b1 (keep b1), a1*b2, a2*b1 ----
            bf16x8 a1[4], a2[4], b1v[8];
            #pragma unroll
            for (int mt = 0; mt < 4; ++mt)
                a1[mt] = *(const bf16x8*)&As[((size_t)(0 * 4 + quad) * 64 + mt * 16 + lm) * 8];
            #pragma unroll
            for (int nt = 0; nt < 8; ++nt) {
                b1v[nt] = *(const bf16x8*)&Bs[((size_t)(0 * 4 + quad) * 512 + wave * 128 + nt * 16 + lm) * 8];
                #pragma unroll
                for (int mt = 0; mt < 4; ++mt)
                    acc[mt][nt] = __builtin_amdgcn_mfma_f32_16x16x32_bf16(a1[mt], b1v[nt], acc[mt][nt], 0, 0, 0);
            }
            #pragma unroll
            for (int nt = 0; nt < 8; ++nt) {
                bf16x8 b2 = *(const bf16x8*)&Bs[((size_t)(1 * 4 + quad) * 512 + wave * 128 + nt * 16 + lm) * 8];
                #pragma unroll
                for (int mt = 0; mt < 4; ++mt)
                    acc[mt][nt] = __builtin_amdgcn_mfma_f32_16x16x32_bf16(a1[mt], b2, acc[mt][nt], 0, 0, 0);
            }
            #pragma unroll
            for (int mt = 0; mt < 4; ++mt)
                a2[mt] = *(const bf16x8*)&As[((size_t)(1 * 4 + quad) * 64 + mt * 16 + lm) * 8];
            #pragma unroll
            for (int nt = 0; nt < 8; ++nt)
                #pragma unroll
                for (int mt = 0; mt < 4; ++mt)
                    acc[mt][nt] = __builtin_amdgcn_mfma_f32_16x16x32_bf16(a2[mt], b1v[nt], acc[mt][nt], 0, 0, 0);
        }

        // ---- epilogue: per-wave top-2 over its 128 codes, cross-wave merge ----
        const int kbase = wave * 128;
        float e2v[8];
        #pragma unroll
        for (int nt = 0; nt < 8; ++nt) e2v[nt] = e2[kbase + nt * 16 + lm];

        #pragma unroll
        for (int mt = 0; mt < 4; ++mt) {
            #pragma unroll
            for (int r = 0; r < 4; ++r) {
                float v1 = __builtin_inff(), v2 = __builtin_inff();
                int k1 = 0x7fffffff, k2 = 0x7fffffff;
                #pragma unroll
                for (int nt = 0; nt < 8; ++nt) {
                    float v = fmaf(-2.f, acc[mt][nt][r], e2v[nt]);
                    ins2(v, kbase + nt * 16 + lm, v1, k1, v2, k2);
                }
                #pragma unroll
                for (int m = 1; m < 16; m <<= 1) {
                    float ov1 = __shfl_xor(v1, m); int ok1 = __shfl_xor(k1, m);
                    float ov2 = __shfl_xor(v2, m); int ok2 = __shfl_xor(k2, m);
                    ins2(ov1, ok1, v1, k1, v2, k2);
                    ins2(ov2, ok2, v1, k1, v2, k2);
                }
                if (lm == 0) {
                    P2 p; p.v1 = v1; p.k1 = k1; p.v2 = v2; p.k2 = k2;
                    mergebuf[wave * 64 + mt * 16 + quad * 4 + r] = p;
                }
            }
        }
        __syncthreads();

        if (tid < 64) {
            float v1 = __builtin_inff(), v2 = __builtin_inff();
            int k1 = 0x7fffffff, k2 = 0x7fffffff;
            #pragma unroll
            for (int w = 0; w < 4; ++w) {
                P2 p = mergebuf[w * 64 + tid];
                ins2(p.v1, p.k1, v1, k1, v2, k2);
                ins2(p.v2, p.k2, v1, k1, v2, k2);
            }
            int row = Mtile * 64 + tid;
            idx[row] = k1;
            d2[row] = x2[row] + v1;
            if (v2 - v1 < MARGIN) {                 // near-tie -> refine queue
                int qe = atomicAdd(qcount, 1);
                if (qe < QCAP) queue[qe] = make_int2(row, (k1 << 16) | k2);
            }
        }
    }
}

// ---------------- kernel 4: exact fp64 refine of queued near-ties -------------
// One block per entry (strided); 256 threads load the row's channels in parallel.
__global__ void refine_kernel(const int2* __restrict__ queue, const int* __restrict__ qcount,
                              const float* __restrict__ pq, const float* __restrict__ cb,
                              int* __restrict__ idx, float* __restrict__ d2) {
    __shared__ double red[8];
    int cnt = *qcount; if (cnt > QCAP) cnt = QCAP;
    const int tid = threadIdx.x, wave = tid >> 6, lane = tid & 63;
    for (int e = blockIdx.x; e < cnt; e += gridDim.x) {
        int2 ent = queue[e];
        int row = ent.x, k1 = ent.y >> 16, k2 = ent.y & 0xffff;
        int b = row >> 12, s = row & 4095;
        double xv = (double)pq[(size_t)b * (C_ * N_) + (size_t)tid * N_ + s];
        double ea = xv - (double)cb[(size_t)k1 * C_ + tid];
        double eb = xv - (double)cb[(size_t)k2 * C_ + tid];
        double da = ea * ea, db = eb * eb;
        #pragma unroll
        for (int off = 32; off; off >>= 1) {
            da += __shfl_down(da, off);
            db += __shfl_down(db, off);
        }
        if (lane == 0) { red[wave] = da; red[4 + wave] = db; }
        __syncthreads();
        if (tid == 0) {
            double DA = red[0] + red[1] + red[2] + red[3];
            double DB = red[4] + red[5] + red[6] + red[7];
            if (DB < DA || (DB == DA && k2 < k1)) { idx[row] = k2; d2[row] = (float)DB; }
            else { idx[row] = k1; d2[row] = (float)DA; }
        }
        __syncthreads();
    }
}

// ---------------- kernel 5: gather + transpose-write + loss sum ---------------
__global__ void scatter_kernel(const float* __restrict__ cb, const int* __restrict__ idx,
                               const float* __restrict__ d2,
                               double* __restrict__ lossAcc, float* __restrict__ out) {
    int ntile = blockIdx.x, b = blockIdx.y, tid = threadIdx.x;
    int wave = tid >> 6;
    __shared__ int idxs[64];
    __shared__ double lred[4];
    __shared__ float tile[64][65];

    double myloss = 0.0;
    if (tid < 64) {
        int p = ntile * 64 + tid;                   // output flat spatial pos
        int s = ((p & 63) << 6) | (p >> 6);         // sigma (involution)
        int row = (b << 12) | s;
        idxs[tid] = idx[row];
        myloss = (double)d2[row];
    }
    double sd = myloss;
    #pragma unroll
    for (int off = 32; off; off >>= 1) sd += __shfl_down(sd, off);
    if ((tid & 63) == 0) lred[wave] = sd;
    __syncthreads();
    if (tid == 0) atomicAdd(lossAcc, lred[0] + lred[1] + lred[2] + lred[3]);

    for (int cc = 0; cc < 4; ++cc) {
        int c0 = cc * 64;
        #pragma unroll
        for (int pp = 0; pp < 16; ++pp) {
            int i = pp * 4 + (tid >> 6);
            int c = tid & 63;
            tile[i][c] = cb[(size_t)idxs[i] * C_ + c0 + c];   // coalesced rows
        }
        __syncthreads();
        #pragma unroll
        for (int pp = 0; pp < 16; ++pp) {
            int cl = pp * 4 + (tid >> 6);
            int nl = tid & 63;
            out[((size_t)(b * C_ + c0 + cl)) * N_ + ntile * 64 + nl] = tile[nl][cl];
        }
        __syncthreads();
    }
}

// ---------------- kernel 6: loss finalize ------------------------------------
__global__ void finalize_kernel(const double* __restrict__ lossAcc, float* __restrict__ out) {
    out[(size_t)B_ * C_ * N_] =
        (float)(1.25 * (*lossAcc) / (double)((size_t)B_ * N_ * C_));
}

// ---------------- launch ------------------------------------------------------
extern "C" void kernel_launch(void* const* d_in, const int* in_sizes, int n_in,
                              void* d_out, int out_size, void* d_ws, size_t ws_size,
                              hipStream_t stream) {
    const float* pq = (const float*)d_in[0];   // [16,256,64,64]
    const float* cb = (const float*)d_in[1];   // [512,256]
    float* out = (float*)d_out;                // 16777216 out + 1 loss
    char* ws = (char*)d_ws;
    double* lossAcc = (double*)ws;                      // 8 B
    int*    qcount  = (int*)(ws + 8);                   // 4 B
    float*  e2      = (float*)(ws + 64);                // 2 KB
    float*  x2      = (float*)(ws + 4096);              // 256 KB
    float*  d2      = (float*)(ws + 4096 + 262144);     // 256 KB
    int*    idx     = (int*)(ws + 4096 + 2 * 262144);   // 256 KB
    __bf16* Bpack   = (__bf16*)(ws + 4096 + 3 * 262144);            // 512 KB
    int2*   queue   = (int2*)(ws + 4096 + 3 * 262144 + 524288);     // 64 KB
    // Apack (64 MiB) lives in d_out[0 .. 16777215]; scatter overwrites it later.
    __bf16* Apack   = (__bf16*)d_out;

    prep_kernel<<<K_, 64, 0, stream>>>(cb, e2, Bpack, lossAcc, qcount);
    pack_kernel<<<1024, 256, 0, stream>>>(pq, Apack, x2);
    main_kernel<<<512, 256, 0, stream>>>(Apack, Bpack, e2, x2, idx, d2, queue, qcount);
    refine_kernel<<<64, 256, 0, stream>>>(queue, qcount, pq, cb, idx, d2);
    scatter_kernel<<<dim3(HW_, B_), 256, 0, stream>>>(cb, idx, d2, lossAcc, out);
    finalize_kernel<<<1, 1, 0, stream>>>(lossAcc, out);
}